// Round 2
// baseline (2956.173 us; speedup 1.0000x reference)
//
#include <hip/hip_runtime.h>
#include <math.h>

#define N_RES 512
#define CS 384
#define CZ 128
#define HD 12
#define CH 16
#define NPQ 4
#define NPV 8
#define QKV_DIM 1152   // 192 q + 384 kv + 144 qp + 432 kvp
#define CAT_DIM 2112   // 192 o + 288 fl + 96 norm + 1536 opair
#define INF_F 100000.0f

// ---------------- generic f32 GEMM: out = act(A[M,K] @ W[Nn,K]^T + bias (+res)) ----
// requires M%32==0, Nn%32==0, K%32==0 (all shapes here satisfy this)
__global__ __launch_bounds__(256) void gemm_kernel(
    const float* __restrict__ A, const float* __restrict__ W,
    const float* __restrict__ bias, const float* res, float* out,
    int M, int Nn, int K, int relu)
{
    __shared__ float As[32][33];
    __shared__ float Ws[32][33];
    int bm = blockIdx.y * 32;
    int bn = blockIdx.x * 32;
    int tid = threadIdx.x;
    int tx = tid & 15, ty = tid >> 4;
    float acc00 = 0.f, acc01 = 0.f, acc10 = 0.f, acc11 = 0.f;
    int ar = tid >> 3;            // 0..31
    int ak = (tid & 7) * 4;       // 0..28 step 4
    for (int k0 = 0; k0 < K; k0 += 32) {
        float4 av = *(const float4*)(A + (size_t)(bm + ar) * K + k0 + ak);
        float4 wv = *(const float4*)(W + (size_t)(bn + ar) * K + k0 + ak);
        As[ar][ak] = av.x; As[ar][ak+1] = av.y; As[ar][ak+2] = av.z; As[ar][ak+3] = av.w;
        Ws[ar][ak] = wv.x; Ws[ar][ak+1] = wv.y; Ws[ar][ak+2] = wv.z; Ws[ar][ak+3] = wv.w;
        __syncthreads();
        #pragma unroll
        for (int kk = 0; kk < 32; ++kk) {
            float a0 = As[ty][kk], a1 = As[ty + 16][kk];
            float b0 = Ws[tx][kk], b1 = Ws[tx + 16][kk];
            acc00 += a0 * b0; acc01 += a0 * b1;
            acc10 += a1 * b0; acc11 += a1 * b1;
        }
        __syncthreads();
    }
    #pragma unroll
    for (int i = 0; i < 2; ++i) {
        #pragma unroll
        for (int j = 0; j < 2; ++j) {
            float v = (i == 0 ? (j == 0 ? acc00 : acc01) : (j == 0 ? acc10 : acc11));
            int m = bm + ty + i * 16;
            int n = bn + tx + j * 16;
            v += bias[n];
            if (res) v += res[(size_t)m * Nn + n];
            if (relu) v = fmaxf(v, 0.f);
            out[(size_t)m * Nn + n] = v;
        }
    }
}

// ---------------- row LayerNorm over CS=384 (block=64 threads, one row/block) ------
__global__ __launch_bounds__(64) void rowln_kernel(
    const float* in, float* out, const float* __restrict__ g, const float* __restrict__ b)
{
    int row = blockIdx.x;
    int lane = threadIdx.x;
    const float* x = in + (size_t)row * CS;
    float v[6];
    float s = 0.f, sq = 0.f;
    #pragma unroll
    for (int k = 0; k < 6; ++k) {
        v[k] = x[lane + k * 64];
        s += v[k]; sq += v[k] * v[k];
    }
    #pragma unroll
    for (int off = 32; off; off >>= 1) { s += __shfl_xor(s, off); sq += __shfl_xor(sq, off); }
    float mean = s * (1.0f / CS);
    float var = sq * (1.0f / CS) - mean * mean;
    float rstd = 1.0f / sqrtf(var + 1e-5f);
    float* o = out + (size_t)row * CS;
    #pragma unroll
    for (int k = 0; k < 6; ++k) {
        int c = lane + k * 64;
        o[c] = (v[k] - mean) * rstd * g[c] + b[c];
    }
}

// ---------------- z row stats (mean, rstd) over CZ=128, one wave per row ----------
__global__ __launch_bounds__(256) void zstats_kernel(const float* __restrict__ z, float* __restrict__ zstats)
{
    int wid = threadIdx.x >> 6;
    int lane = threadIdx.x & 63;
    size_t row = (size_t)blockIdx.x * 4 + wid;
    const float* x = z + row * CZ;
    float a = x[lane], b = x[lane + 64];
    float s = a + b, sq = a * a + b * b;
    #pragma unroll
    for (int off = 32; off; off >>= 1) { s += __shfl_xor(s, off); sq += __shfl_xor(sq, off); }
    if (lane == 0) {
        float mean = s * (1.0f / CZ);
        float var = sq * (1.0f / CZ) - mean * mean;
        zstats[row * 2] = mean;
        zstats[row * 2 + 1] = 1.0f / sqrtf(var + 1e-5f);
    }
}

// ---------------- pair bias (+mask) precompute: bpair[h][i][j] ---------------------
__global__ __launch_bounds__(256) void bpair_kernel(
    const float* __restrict__ z, const float* __restrict__ zstats,
    const float* __restrict__ lng, const float* __restrict__ lnb,
    const float* __restrict__ w_b, const float* __restrict__ b_b,
    const float* __restrict__ mask, float* __restrict__ bpair)
{
    __shared__ float wbs[HD][CZ];
    __shared__ float gs[CZ], bs[CZ];
    for (int idx = threadIdx.x; idx < HD * CZ; idx += 256) wbs[idx / CZ][idx % CZ] = w_b[idx];
    if (threadIdx.x < CZ) { gs[threadIdx.x] = lng[threadIdx.x]; bs[threadIdx.x] = lnb[threadIdx.x]; }
    __syncthreads();
    size_t row = (size_t)blockIdx.x * 256 + threadIdx.x;   // i*512 + j
    int i = (int)(row >> 9), j = (int)(row & 511);
    const float* zr = z + row * CZ;
    float m = zstats[row * 2], r = zstats[row * 2 + 1];
    float acc[HD];
    #pragma unroll
    for (int h = 0; h < HD; ++h) acc[h] = 0.f;
    for (int c = 0; c < CZ; c += 4) {
        float4 zv = *(const float4*)(zr + c);
        float zn0 = (zv.x - m) * r * gs[c] + bs[c];
        float zn1 = (zv.y - m) * r * gs[c+1] + bs[c+1];
        float zn2 = (zv.z - m) * r * gs[c+2] + bs[c+2];
        float zn3 = (zv.w - m) * r * gs[c+3] + bs[c+3];
        #pragma unroll
        for (int h = 0; h < HD; ++h)
            acc[h] += zn0 * wbs[h][c] + zn1 * wbs[h][c+1] + zn2 * wbs[h][c+2] + zn3 * wbs[h][c+3];
    }
    float mterm = INF_F * (mask[i] * mask[j] - 1.0f);
    #pragma unroll
    for (int h = 0; h < HD; ++h)
        bpair[((size_t)h * N_RES + i) * N_RES + j] = 0.57735026919f * (acc[h] + b_b[h]) + mterm;
}

// ---------------- pack qkv weights [w_q; w_kv; w_qp; w_kvp] ------------------------
__global__ __launch_bounds__(256) void pack_kernel(
    const float* __restrict__ w_q, const float* __restrict__ w_kv,
    const float* __restrict__ w_qp, const float* __restrict__ w_kvp,
    const float* __restrict__ b_q, const float* __restrict__ b_kv,
    const float* __restrict__ b_qp, const float* __restrict__ b_kvp,
    float* __restrict__ wqkv, float* __restrict__ bqkv)
{
    int idx = blockIdx.x * 256 + threadIdx.x;
    if (idx < QKV_DIM * CS) {
        int rowi = idx / CS, col = idx % CS;
        float v;
        if (rowi < 192) v = w_q[rowi * CS + col];
        else if (rowi < 576) v = w_kv[(rowi - 192) * CS + col];
        else if (rowi < 720) v = w_qp[(rowi - 576) * CS + col];
        else v = w_kvp[(rowi - 720) * CS + col];
        wqkv[idx] = v;
    }
    if (idx < QKV_DIM) {
        float v;
        if (idx < 192) v = b_q[idx];
        else if (idx < 576) v = b_kv[idx - 192];
        else if (idx < 720) v = b_qp[idx - 576];
        else v = b_kvp[idx - 720];
        bqkv[idx] = v;
    }
}

// ---------------- init quats (normalize) and trans (/SCALE) ------------------------
__global__ void init_kernel(const float* __restrict__ rq, const float* __restrict__ rt,
                            float* __restrict__ quats, float* __restrict__ trans)
{
    int i = blockIdx.x * 256 + threadIdx.x;
    if (i < N_RES) {
        float w = rq[i*4], x = rq[i*4+1], y = rq[i*4+2], z = rq[i*4+3];
        float n = 1.0f / sqrtf(w*w + x*x + y*y + z*z);
        quats[i*4] = w*n; quats[i*4+1] = x*n; quats[i*4+2] = y*n; quats[i*4+3] = z*n;
        trans[i*3] = rt[i*3] * 0.1f; trans[i*3+1] = rt[i*3+1] * 0.1f; trans[i*3+2] = rt[i*3+2] * 0.1f;
    }
}

// ---------------- quats -> rot matrix ---------------------------------------------
__global__ void rot_kernel(const float* __restrict__ quats, float* __restrict__ rot)
{
    int i = blockIdx.x * 256 + threadIdx.x;
    if (i < N_RES) {
        float w = quats[i*4], x = quats[i*4+1], y = quats[i*4+2], z = quats[i*4+3];
        float n = 1.0f / sqrtf(w*w + x*x + y*y + z*z);
        w *= n; x *= n; y *= n; z *= n;
        float* R = rot + i * 9;
        R[0] = 1 - 2*(y*y + z*z); R[1] = 2*(x*y - w*z);     R[2] = 2*(x*z + w*y);
        R[3] = 2*(x*y + w*z);     R[4] = 1 - 2*(x*x + z*z); R[5] = 2*(y*z - w*x);
        R[6] = 2*(x*z - w*y);     R[7] = 2*(y*z + w*x);     R[8] = 1 - 2*(x*x + y*y);
    }
}

// ---------------- point transforms + vcat assembly ---------------------------------
// qpts/kpts: [i][h][p][3] (per-head stride 12 floats); vcat: [j][h][40] = 16 v + 24 v_pts
__global__ __launch_bounds__(192) void transform_kernel(
    const float* __restrict__ qkv, const float* __restrict__ rot, const float* __restrict__ trans,
    float* __restrict__ qpts, float* __restrict__ kpts, float* __restrict__ vcat)
{
    int i = blockIdx.x, t = threadIdx.x;
    const float* R = rot + i * 9;
    float r0 = R[0], r1 = R[1], r2 = R[2], r3 = R[3], r4 = R[4], r5 = R[5], r6 = R[6], r7 = R[7], r8 = R[8];
    float tx = trans[i*3], ty = trans[i*3+1], tz = trans[i*3+2];
    const float* row = qkv + (size_t)i * QKV_DIM;
    if (t < 48) {               // q points: channel = 576 + x*48 + h*4 + pp ; t = h*4+pp
        float lx = row[576 + t], ly = row[576 + 48 + t], lz = row[576 + 96 + t];
        float gx = r0*lx + r1*ly + r2*lz + tx;
        float gy = r3*lx + r4*ly + r5*lz + ty;
        float gz = r6*lx + r7*ly + r8*lz + tz;
        float* o = qpts + (size_t)i * 144 + t * 3;    // h*12 + pp*3
        o[0] = gx; o[1] = gy; o[2] = gz;
    }
    if (t < 144) {              // kv points: channel = 720 + x*144 + h*12 + pp ; t = h*12+pp
        int h = t / 12, pp = t % 12;
        float lx = row[720 + t], ly = row[720 + 144 + t], lz = row[720 + 288 + t];
        float gx = r0*lx + r1*ly + r2*lz + tx;
        float gy = r3*lx + r4*ly + r5*lz + ty;
        float gz = r6*lx + r7*ly + r8*lz + tz;
        if (pp < 4) {
            // k_pts layout [i][h][pp][x]: offset h*12 + pp*3  (round-1 bug: was (h*12+pp)*3, OOB)
            float* o = kpts + (size_t)i * 144 + h * 12 + pp * 3;
            o[0] = gx; o[1] = gy; o[2] = gz;
        } else {
            float* o = vcat + (size_t)i * 480 + h * 40 + 16 + (pp - 4) * 3;
            o[0] = gx; o[1] = gy; o[2] = gz;
        }
    }
    {                           // v channels: kv section, second half of each 32
        int h = t >> 4, c = t & 15;
        vcat[(size_t)i * 480 + h * 40 + c] = row[192 + h * 32 + 16 + c];
    }
}

// ---------------- attention logits + softmax: a[h][i][j] ---------------------------
__global__ __launch_bounds__(256) void attn_kernel(
    const float* __restrict__ qkv, const float* __restrict__ qpts, const float* __restrict__ kpts,
    const float* __restrict__ bpair, const float* __restrict__ head_weights, float* __restrict__ a)
{
    int i = blockIdx.x, h = blockIdx.y;
    __shared__ float qs[CH], qps[12], shw[1];
    __shared__ float redm[4], reds[4];
    int t = threadIdx.x;
    if (t < CH) qs[t] = qkv[(size_t)i * QKV_DIM + h * CH + t];
    else if (t < CH + 12) qps[t - CH] = qpts[(size_t)i * 144 + h * 12 + (t - CH)];
    else if (t == 31) {
        float x = head_weights[h];
        float sp = (x > 20.f) ? x : log1pf(expf(x));
        shw[0] = sp * 0.13608276348f;   // softplus(hw) * sqrt(1/54)
    }
    __syncthreads();
    float hw = shw[0];
    float xv[2];
    #pragma unroll
    for (int r = 0; r < 2; ++r) {
        int j = t + r * 256;
        const float* kr = qkv + (size_t)j * QKV_DIM + 192 + h * 32;
        float dot = 0.f;
        #pragma unroll
        for (int c = 0; c < CH; ++c) dot += qs[c] * kr[c];
        const float* kp = kpts + (size_t)j * 144 + h * 12;
        float pt = 0.f;
        #pragma unroll
        for (int pc = 0; pc < 12; ++pc) { float d = qps[pc] - kp[pc]; pt += d * d; }
        xv[r] = dot * 0.14433756730f + bpair[((size_t)h * N_RES + i) * N_RES + j] - 0.5f * hw * pt;
    }
    float lm = fmaxf(xv[0], xv[1]);
    #pragma unroll
    for (int off = 32; off; off >>= 1) lm = fmaxf(lm, __shfl_xor(lm, off));
    if ((t & 63) == 0) redm[t >> 6] = lm;
    __syncthreads();
    float bmx = fmaxf(fmaxf(redm[0], redm[1]), fmaxf(redm[2], redm[3]));
    float e0 = expf(xv[0] - bmx), e1 = expf(xv[1] - bmx);
    float ls = e0 + e1;
    #pragma unroll
    for (int off = 32; off; off >>= 1) ls += __shfl_xor(ls, off);
    if ((t & 63) == 0) reds[t >> 6] = ls;
    __syncthreads();
    float inv = 1.0f / (reds[0] + reds[1] + reds[2] + reds[3]);
    float* arow = a + ((size_t)h * N_RES + i) * N_RES;
    arow[t] = e0 * inv;
    arow[t + 256] = e1 * inv;
}

// ---------------- o_tmp[h][i][40] = sum_j a[h][i][j] * vcat[j][h][40] --------------
__global__ __launch_bounds__(256) void ogemm_kernel(
    const float* __restrict__ a, const float* __restrict__ vcat, float* __restrict__ o_tmp)
{
    int h = blockIdx.y;
    int bm = blockIdx.x * 64;
    __shared__ float As[64][33];
    __shared__ float Vs[32][40];
    int t = threadIdx.x;
    int il_c = t & 63, ng = t >> 6;
    float acc[10];
    #pragma unroll
    for (int r = 0; r < 10; ++r) acc[r] = 0.f;
    for (int j0 = 0; j0 < N_RES; j0 += 32) {
        {
            int l = t * 8;
            int il = l >> 5, jl = l & 31;
            const float4* src = (const float4*)(a + ((size_t)h * N_RES + bm + il) * N_RES + j0 + jl);
            float4 v0 = src[0], v1 = src[1];
            As[il][jl]   = v0.x; As[il][jl+1] = v0.y; As[il][jl+2] = v0.z; As[il][jl+3] = v0.w;
            As[il][jl+4] = v1.x; As[il][jl+5] = v1.y; As[il][jl+6] = v1.z; As[il][jl+7] = v1.w;
        }
        #pragma unroll
        for (int r = 0; r < 5; ++r) {
            int l = t + 256 * r;
            int jj = l / 40, n = l % 40;
            Vs[jj][n] = vcat[(size_t)(j0 + jj) * 480 + h * 40 + n];
        }
        __syncthreads();
        #pragma unroll 8
        for (int jj = 0; jj < 32; ++jj) {
            float av = As[il_c][jj];
            #pragma unroll
            for (int r = 0; r < 10; ++r) acc[r] += av * Vs[jj][ng * 10 + r];
        }
        __syncthreads();
    }
    float* o = o_tmp + ((size_t)h * N_RES + bm + il_c) * 40 + ng * 10;
    #pragma unroll
    for (int r = 0; r < 10; ++r) o[r] = acc[r];
}

// ---------------- o_pair: cat[i][576 + h*128 + c] = sum_j a[h][i][j]*zln[i][j][c] --
__global__ __launch_bounds__(128) void opair_kernel(
    const float* __restrict__ z, const float* __restrict__ zstats, const float* __restrict__ a,
    const float* __restrict__ lng, const float* __restrict__ lnb, float* __restrict__ cat)
{
    int i = blockIdx.x;
    int c = threadIdx.x;   // 128
    __shared__ float als[HD][N_RES];
    __shared__ float zst[N_RES * 2];
    for (int idx = c; idx < HD * N_RES; idx += 128) {
        int h = idx >> 9, j = idx & 511;
        als[h][j] = a[((size_t)h * N_RES + i) * N_RES + j];
    }
    for (int idx = c; idx < N_RES * 2; idx += 128) zst[idx] = zstats[(size_t)i * N_RES * 2 + idx];
    __syncthreads();
    float g = lng[c], b = lnb[c];
    float acc[HD];
    #pragma unroll
    for (int h = 0; h < HD; ++h) acc[h] = 0.f;
    const float* zr = z + (size_t)i * N_RES * CZ + c;
    for (int j = 0; j < N_RES; ++j) {
        float m = zst[j * 2], r = zst[j * 2 + 1];
        float zn = (zr[(size_t)j * CZ] - m) * r * g + b;
        #pragma unroll
        for (int h = 0; h < HD; ++h) acc[h] += als[h][j] * zn;
    }
    float* o = cat + (size_t)i * CAT_DIM + 576;
    #pragma unroll
    for (int h = 0; h < HD; ++h) o[h * CZ + c] = acc[h];
}

// ---------------- cat[0:576): o copy + local frame points + norms ------------------
__global__ __launch_bounds__(192) void cat_kernel(
    const float* __restrict__ o_tmp, const float* __restrict__ rot, const float* __restrict__ trans,
    float* __restrict__ cat)
{
    int i = blockIdx.x, t = threadIdx.x;
    const float* R = rot + i * 9;
    float tx = trans[i*3], ty = trans[i*3+1], tz = trans[i*3+2];
    float* crow = cat + (size_t)i * CAT_DIM;
    {   // o channels: t = h*16 + c
        int h = t >> 4, c = t & 15;
        crow[t] = o_tmp[((size_t)h * N_RES + i) * 40 + c];
    }
    if (t < 96) {   // t = h*8 + p
        int h = t >> 3, p = t & 7;
        const float* og = o_tmp + ((size_t)h * N_RES + i) * 40 + 16 + p * 3;
        float dx = og[0] - tx, dy = og[1] - ty, dz = og[2] - tz;
        float lx = R[0]*dx + R[3]*dy + R[6]*dz;   // rot^T
        float ly = R[1]*dx + R[4]*dy + R[7]*dz;
        float lz = R[2]*dx + R[5]*dy + R[8]*dz;
        crow[192 + t] = lx;
        crow[288 + t] = ly;
        crow[384 + t] = lz;
        crow[480 + t] = sqrtf(lx*lx + ly*ly + lz*lz + 1e-8f);
    }
}

// ---------------- backbone update: upd, quat mul+norm, trans, frame out ------------
__global__ __launch_bounds__(256) void frame_kernel(
    const float* __restrict__ s, const float* __restrict__ w_bb, const float* __restrict__ b_bb,
    const float* __restrict__ rot, float* quats, float* trans, float* __restrict__ frames_out)
{
    int lane = threadIdx.x & 63;
    int i = (blockIdx.x * 256 + threadIdx.x) >> 6;
    const float* srow = s + (size_t)i * CS;
    float p[6];
    #pragma unroll
    for (int r = 0; r < 6; ++r) p[r] = 0.f;
    #pragma unroll
    for (int k = 0; k < 6; ++k) {
        int c = lane + k * 64;
        float sv = srow[c];
        #pragma unroll
        for (int r = 0; r < 6; ++r) p[r] += sv * w_bb[r * CS + c];
    }
    #pragma unroll
    for (int r = 0; r < 6; ++r)
        #pragma unroll
        for (int off = 32; off; off >>= 1) p[r] += __shfl_xor(p[r], off);
    if (lane == 0) {
        float u0 = p[0] + b_bb[0], u1 = p[1] + b_bb[1], u2 = p[2] + b_bb[2];
        float u3 = p[3] + b_bb[3], u4 = p[4] + b_bb[4], u5 = p[5] + b_bb[5];
        float qw = quats[i*4], qx = quats[i*4+1], qy = quats[i*4+2], qz = quats[i*4+3];
        float nw = qw - qx*u0 - qy*u1 - qz*u2;
        float nx = qw*u0 + qx + qy*u2 - qz*u1;
        float ny = qw*u1 - qx*u2 + qy + qz*u0;
        float nz = qw*u2 + qx*u1 - qy*u0 + qz;
        float n = 1.0f / sqrtf(nw*nw + nx*nx + ny*ny + nz*nz);
        nw *= n; nx *= n; ny *= n; nz *= n;
        const float* R = rot + i * 9;
        float t0 = trans[i*3+0] + R[0]*u3 + R[1]*u4 + R[2]*u5;
        float t1 = trans[i*3+1] + R[3]*u3 + R[4]*u4 + R[5]*u5;
        float t2 = trans[i*3+2] + R[6]*u3 + R[7]*u4 + R[8]*u5;
        quats[i*4] = nw; quats[i*4+1] = nx; quats[i*4+2] = ny; quats[i*4+3] = nz;
        trans[i*3] = t0; trans[i*3+1] = t1; trans[i*3+2] = t2;
        float* f = frames_out + (size_t)i * 7;
        f[0] = nw; f[1] = nx; f[2] = ny; f[3] = nz;
        f[4] = t0 * 10.f; f[5] = t1 * 10.f; f[6] = t2 * 10.f;
    }
}

extern "C" void kernel_launch(void* const* d_in, const int* in_sizes, int n_in,
                              void* d_out, int out_size, void* d_ws, size_t ws_size,
                              hipStream_t stream)
{
    const float* s_in  = (const float*)d_in[0];
    const float* z     = (const float*)d_in[1];
    const float* rq    = (const float*)d_in[2];
    const float* rt    = (const float*)d_in[3];
    const float* mask  = (const float*)d_in[4];
    const float* ln_s_g = (const float*)d_in[5];
    const float* ln_s_b = (const float*)d_in[6];
    const float* ln_z_g = (const float*)d_in[7];
    const float* ln_z_b = (const float*)d_in[8];
    const float* w_in  = (const float*)d_in[9];
    const float* b_in  = (const float*)d_in[10];
    const float* w_q   = (const float*)d_in[11];
    const float* b_q   = (const float*)d_in[12];
    const float* w_kv  = (const float*)d_in[13];
    const float* b_kv  = (const float*)d_in[14];
    const float* w_qp  = (const float*)d_in[15];
    const float* b_qp  = (const float*)d_in[16];
    const float* w_kvp = (const float*)d_in[17];
    const float* b_kvp = (const float*)d_in[18];
    const float* w_b   = (const float*)d_in[19];
    const float* b_b   = (const float*)d_in[20];
    const float* head_weights = (const float*)d_in[21];
    const float* w_o   = (const float*)d_in[22];
    const float* b_o   = (const float*)d_in[23];
    const float* ln_ipa_g = (const float*)d_in[24];
    const float* ln_ipa_b = (const float*)d_in[25];
    const float* ln_tr_g  = (const float*)d_in[26];
    const float* ln_tr_b  = (const float*)d_in[27];
    const float* w_t1  = (const float*)d_in[28];
    const float* b_t1  = (const float*)d_in[29];
    const float* w_t2  = (const float*)d_in[30];
    const float* b_t2  = (const float*)d_in[31];
    const float* w_t3  = (const float*)d_in[32];
    const float* b_t3  = (const float*)d_in[33];
    const float* w_bb  = (const float*)d_in[34];
    const float* b_bb  = (const float*)d_in[35];

    float* ws = (float*)d_ws;
    size_t off = 0;
    auto alloc = [&](size_t n) { float* p = ws + off; off += n; return p; };
    float* s_tmp   = alloc((size_t)N_RES * CS);
    float* t1      = alloc((size_t)N_RES * CS);
    float* t2      = alloc((size_t)N_RES * CS);
    float* zstats  = alloc((size_t)N_RES * N_RES * 2);
    float* bpair   = alloc((size_t)HD * N_RES * N_RES);
    float* abuf    = alloc((size_t)HD * N_RES * N_RES);
    float* qkv_all = alloc((size_t)N_RES * QKV_DIM);
    float* qpts    = alloc((size_t)N_RES * 144);
    float* kpts    = alloc((size_t)N_RES * 144);
    float* vcat    = alloc((size_t)N_RES * 480);
    float* o_tmp   = alloc((size_t)HD * N_RES * 40);
    float* cat     = alloc((size_t)N_RES * CAT_DIM);
    float* quats   = alloc((size_t)N_RES * 4);
    float* trans   = alloc((size_t)N_RES * 3 + 1);   // +1 keeps later bufs 16B-aligned
    float* rot     = alloc((size_t)N_RES * 9 + 3);
    float* wqkv    = alloc((size_t)QKV_DIM * CS);
    float* bqkv    = alloc((size_t)QKV_DIM);
    float* s_cur   = alloc((size_t)N_RES * CS);
    (void)ws_size; (void)in_sizes; (void)n_in; (void)out_size;

    // ---- preamble ----
    init_kernel<<<2, 256, 0, stream>>>(rq, rt, quats, trans);
    rowln_kernel<<<N_RES, 64, 0, stream>>>(s_in, s_tmp, ln_s_g, ln_s_b);
    gemm_kernel<<<dim3(CS / 32, N_RES / 32), 256, 0, stream>>>(s_tmp, w_in, b_in, nullptr, s_cur, N_RES, CS, CS, 0);
    zstats_kernel<<<(N_RES * N_RES) / 4, 256, 0, stream>>>(z, zstats);
    bpair_kernel<<<(N_RES * N_RES) / 256, 256, 0, stream>>>(z, zstats, ln_z_g, ln_z_b, w_b, b_b, mask, bpair);
    pack_kernel<<<(QKV_DIM * CS + 255) / 256, 256, 0, stream>>>(w_q, w_kv, w_qp, w_kvp, b_q, b_kv, b_qp, b_kvp, wqkv, bqkv);

    float* frames = (float*)d_out;
    for (int it = 0; it < 8; ++it) {
        rot_kernel<<<2, 256, 0, stream>>>(quats, rot);
        gemm_kernel<<<dim3(QKV_DIM / 32, N_RES / 32), 256, 0, stream>>>(s_cur, wqkv, bqkv, nullptr, qkv_all, N_RES, QKV_DIM, CS, 0);
        transform_kernel<<<N_RES, 192, 0, stream>>>(qkv_all, rot, trans, qpts, kpts, vcat);
        attn_kernel<<<dim3(N_RES, HD), 256, 0, stream>>>(qkv_all, qpts, kpts, bpair, head_weights, abuf);
        ogemm_kernel<<<dim3(N_RES / 64, HD), 256, 0, stream>>>(abuf, vcat, o_tmp);
        opair_kernel<<<N_RES, 128, 0, stream>>>(z, zstats, abuf, ln_z_g, ln_z_b, cat);
        cat_kernel<<<N_RES, 192, 0, stream>>>(o_tmp, rot, trans, cat);
        gemm_kernel<<<dim3(CS / 32, N_RES / 32), 256, 0, stream>>>(cat, w_o, b_o, s_cur, s_cur, N_RES, CS, CAT_DIM, 0);
        rowln_kernel<<<N_RES, 64, 0, stream>>>(s_cur, s_cur, ln_ipa_g, ln_ipa_b);
        gemm_kernel<<<dim3(CS / 32, N_RES / 32), 256, 0, stream>>>(s_cur, w_t1, b_t1, nullptr, t1, N_RES, CS, CS, 1);
        gemm_kernel<<<dim3(CS / 32, N_RES / 32), 256, 0, stream>>>(t1, w_t2, b_t2, nullptr, t2, N_RES, CS, CS, 1);
        gemm_kernel<<<dim3(CS / 32, N_RES / 32), 256, 0, stream>>>(t2, w_t3, b_t3, s_cur, s_cur, N_RES, CS, CS, 0);
        rowln_kernel<<<N_RES, 64, 0, stream>>>(s_cur, s_cur, ln_tr_g, ln_tr_b);
        frame_kernel<<<N_RES / 4, 256, 0, stream>>>(s_cur, w_bb, b_bb, rot, quats, trans, frames + (size_t)it * N_RES * 7);
    }
    hipMemcpyAsync(frames + 8 * N_RES * 7, s_cur, sizeof(float) * N_RES * CS,
                   hipMemcpyDeviceToDevice, stream);
}

// Round 6
// 2352.537 us; speedup vs baseline: 1.2566x; 1.2566x over previous
//
#include <hip/hip_runtime.h>
#include <math.h>

#define N_RES 512
#define CS 384
#define CZ 128
#define HD 12
#define CH 16
#define QKV_DIM 1152   // 192 q + 384 kv + 144 qp + 432 kvp
#define CAT_DIM 2112   // 192 o + 288 fl + 96 norm + 1536 opair
#define INF_F 100000.0f

typedef __attribute__((ext_vector_type(8))) __bf16 bf16x8;
typedef __attribute__((ext_vector_type(4))) float f32x4;

__device__ inline bf16x8 cvt8(float4 a, float4 b) {
    bf16x8 r;
    r[0] = (__bf16)a.x; r[1] = (__bf16)a.y; r[2] = (__bf16)a.z; r[3] = (__bf16)a.w;
    r[4] = (__bf16)b.x; r[5] = (__bf16)b.y; r[6] = (__bf16)b.z; r[7] = (__bf16)b.w;
    return r;
}

// ---------------- MFMA bf16 GEMM: out = act(A[M,K]@W[Nn,K]^T + bias (+res)) -------
// M%64==0, Nn%64==0, K%64==0. Block 256 thr = 4 waves (2x2), 64x64 tile, K-step 64.
// f32 storage, bf16 convert in staging, f32 accumulate. XOR-swizzled LDS (G4).
__global__ __launch_bounds__(256) void gemm_mfma(
    const float* __restrict__ A, const float* __restrict__ W,
    const float* __restrict__ bias, const float* res, float* out,
    int M, int Nn, int K, int relu)
{
    __shared__ __bf16 Asl[64 * 64];
    __shared__ __bf16 Bsl[64 * 64];
    int bm = blockIdx.y * 64;
    int bn = blockIdx.x * 64;
    int tid = threadIdx.x;

    // staging role: row tr (0..63), unit pair tu (units of 8 bf16 along K)
    int tr = tid >> 2;
    int tu = (tid & 3) * 2;
    const float* ga0 = A + (size_t)(bm + tr) * K + tu * 8;
    const float* gb0 = W + (size_t)(bn + tr) * K + tu * 8;

    // compute role
    int lane = tid & 63;
    int w = tid >> 6;
    int wr = w >> 1, wc = w & 1;
    int lr = lane & 15, lg = lane >> 4;
    int arow0 = wr * 32 + lr, arow1 = arow0 + 16;
    int brow0 = wc * 32 + lr, brow1 = brow0 + 16;

    f32x4 acc00 = {0.f, 0.f, 0.f, 0.f}, acc01 = {0.f, 0.f, 0.f, 0.f};
    f32x4 acc10 = {0.f, 0.f, 0.f, 0.f}, acc11 = {0.f, 0.f, 0.f, 0.f};

    float4 ra0, ra1, ra2, ra3, rb0, rb1, rb2, rb3;
    // preload k0 = 0
    ra0 = ((const float4*)ga0)[0]; ra1 = ((const float4*)ga0)[1];
    ra2 = ((const float4*)ga0)[2]; ra3 = ((const float4*)ga0)[3];
    rb0 = ((const float4*)gb0)[0]; rb1 = ((const float4*)gb0)[1];
    rb2 = ((const float4*)gb0)[2]; rb3 = ((const float4*)gb0)[3];

    int u0 = tu ^ (tr & 7);
    int u1 = (tu + 1) ^ (tr & 7);

    for (int k0 = 0; k0 < K; k0 += 64) {
        __syncthreads();   // LDS free from previous compute
        *(bf16x8*)(Asl + tr * 64 + u0 * 8) = cvt8(ra0, ra1);
        *(bf16x8*)(Asl + tr * 64 + u1 * 8) = cvt8(ra2, ra3);
        *(bf16x8*)(Bsl + tr * 64 + u0 * 8) = cvt8(rb0, rb1);
        *(bf16x8*)(Bsl + tr * 64 + u1 * 8) = cvt8(rb2, rb3);
        __syncthreads();
        if (k0 + 64 < K) {   // prefetch next step; latency hides under MFMA below
            const float* ga = ga0 + k0 + 64;
            const float* gb = gb0 + k0 + 64;
            ra0 = ((const float4*)ga)[0]; ra1 = ((const float4*)ga)[1];
            ra2 = ((const float4*)ga)[2]; ra3 = ((const float4*)ga)[3];
            rb0 = ((const float4*)gb)[0]; rb1 = ((const float4*)gb)[1];
            rb2 = ((const float4*)gb)[2]; rb3 = ((const float4*)gb)[3];
        }
        #pragma unroll
        for (int ks = 0; ks < 2; ++ks) {
            int ub = ks * 4 + lg;
            bf16x8 a0 = *(bf16x8*)(Asl + arow0 * 64 + (ub ^ (lr & 7)) * 8);
            bf16x8 a1 = *(bf16x8*)(Asl + arow1 * 64 + (ub ^ (lr & 7)) * 8);
            bf16x8 b0 = *(bf16x8*)(Bsl + brow0 * 64 + (ub ^ (lr & 7)) * 8);
            bf16x8 b1 = *(bf16x8*)(Bsl + brow1 * 64 + (ub ^ (lr & 7)) * 8);
            acc00 = __builtin_amdgcn_mfma_f32_16x16x32_bf16(a0, b0, acc00, 0, 0, 0);
            acc01 = __builtin_amdgcn_mfma_f32_16x16x32_bf16(a0, b1, acc01, 0, 0, 0);
            acc10 = __builtin_amdgcn_mfma_f32_16x16x32_bf16(a1, b0, acc10, 0, 0, 0);
            acc11 = __builtin_amdgcn_mfma_f32_16x16x32_bf16(a1, b1, acc11, 0, 0, 0);
        }
    }

    // epilogue: D col = lane&15, row = (lane>>4)*4 + reg  (m89-verified mapping)
    int mb = bm + wr * 32, nb = bn + wc * 32;
    #pragma unroll
    for (int fm = 0; fm < 2; ++fm) {
        #pragma unroll
        for (int fn = 0; fn < 2; ++fn) {
            f32x4 acc = fm == 0 ? (fn == 0 ? acc00 : acc01) : (fn == 0 ? acc10 : acc11);
            int n = nb + fn * 16 + lr;
            float bi = bias[n];
            int m0 = mb + fm * 16 + lg * 4;
            #pragma unroll
            for (int r = 0; r < 4; ++r) {
                float v = acc[r] + bi;
                if (res) v += res[(size_t)(m0 + r) * Nn + n];
                if (relu) v = fmaxf(v, 0.f);
                out[(size_t)(m0 + r) * Nn + n] = v;
            }
        }
    }
}

// ---------------- row LayerNorm over CS=384 (block=64 threads, one row/block) ------
__global__ __launch_bounds__(64) void rowln_kernel(
    const float* in, float* out, const float* __restrict__ g, const float* __restrict__ b)
{
    int row = blockIdx.x;
    int lane = threadIdx.x;
    const float* x = in + (size_t)row * CS;
    float v[6];
    float s = 0.f, sq = 0.f;
    #pragma unroll
    for (int k = 0; k < 6; ++k) {
        v[k] = x[lane + k * 64];
        s += v[k]; sq += v[k] * v[k];
    }
    #pragma unroll
    for (int off = 32; off; off >>= 1) { s += __shfl_xor(s, off); sq += __shfl_xor(sq, off); }
    float mean = s * (1.0f / CS);
    float var = sq * (1.0f / CS) - mean * mean;
    float rstd = 1.0f / sqrtf(var + 1e-5f);
    float* o = out + (size_t)row * CS;
    #pragma unroll
    for (int k = 0; k < 6; ++k) {
        int c = lane + k * 64;
        o[c] = (v[k] - mean) * rstd * g[c] + b[c];
    }
}

// ---------------- z row stats (mean, rstd) over CZ=128, one wave per row ----------
__global__ __launch_bounds__(256) void zstats_kernel(const float* __restrict__ z, float* __restrict__ zstats)
{
    int wid = threadIdx.x >> 6;
    int lane = threadIdx.x & 63;
    size_t row = (size_t)blockIdx.x * 4 + wid;
    const float* x = z + row * CZ;
    float a = x[lane], b = x[lane + 64];
    float s = a + b, sq = a * a + b * b;
    #pragma unroll
    for (int off = 32; off; off >>= 1) { s += __shfl_xor(s, off); sq += __shfl_xor(sq, off); }
    if (lane == 0) {
        float mean = s * (1.0f / CZ);
        float var = sq * (1.0f / CZ) - mean * mean;
        zstats[row * 2] = mean;
        zstats[row * 2 + 1] = 1.0f / sqrtf(var + 1e-5f);
    }
}

// ---------------- pair bias (+mask) precompute: bpair[h][i][j] ---------------------
__global__ __launch_bounds__(256) void bpair_kernel(
    const float* __restrict__ z, const float* __restrict__ zstats,
    const float* __restrict__ lng, const float* __restrict__ lnb,
    const float* __restrict__ w_b, const float* __restrict__ b_b,
    const float* __restrict__ mask, float* __restrict__ bpair)
{
    __shared__ float wbs[HD][CZ];
    __shared__ float gs[CZ], bs[CZ];
    for (int idx = threadIdx.x; idx < HD * CZ; idx += 256) wbs[idx / CZ][idx % CZ] = w_b[idx];
    if (threadIdx.x < CZ) { gs[threadIdx.x] = lng[threadIdx.x]; bs[threadIdx.x] = lnb[threadIdx.x]; }
    __syncthreads();
    size_t row = (size_t)blockIdx.x * 256 + threadIdx.x;   // i*512 + j
    int i = (int)(row >> 9), j = (int)(row & 511);
    const float* zr = z + row * CZ;
    float m = zstats[row * 2], r = zstats[row * 2 + 1];
    float acc[HD];
    #pragma unroll
    for (int h = 0; h < HD; ++h) acc[h] = 0.f;
    for (int c = 0; c < CZ; c += 4) {
        float4 zv = *(const float4*)(zr + c);
        float zn0 = (zv.x - m) * r * gs[c] + bs[c];
        float zn1 = (zv.y - m) * r * gs[c+1] + bs[c+1];
        float zn2 = (zv.z - m) * r * gs[c+2] + bs[c+2];
        float zn3 = (zv.w - m) * r * gs[c+3] + bs[c+3];
        #pragma unroll
        for (int h = 0; h < HD; ++h)
            acc[h] += zn0 * wbs[h][c] + zn1 * wbs[h][c+1] + zn2 * wbs[h][c+2] + zn3 * wbs[h][c+3];
    }
    float mterm = INF_F * (mask[i] * mask[j] - 1.0f);
    #pragma unroll
    for (int h = 0; h < HD; ++h)
        bpair[((size_t)h * N_RES + i) * N_RES + j] = 0.57735026919f * (acc[h] + b_b[h]) + mterm;
}

// ---------------- pack qkv weights [w_q; w_kv; w_qp; w_kvp] ------------------------
__global__ __launch_bounds__(256) void pack_kernel(
    const float* __restrict__ w_q, const float* __restrict__ w_kv,
    const float* __restrict__ w_qp, const float* __restrict__ w_kvp,
    const float* __restrict__ b_q, const float* __restrict__ b_kv,
    const float* __restrict__ b_qp, const float* __restrict__ b_kvp,
    float* __restrict__ wqkv, float* __restrict__ bqkv)
{
    int idx = blockIdx.x * 256 + threadIdx.x;
    if (idx < QKV_DIM * CS) {
        int rowi = idx / CS, col = idx % CS;
        float v;
        if (rowi < 192) v = w_q[rowi * CS + col];
        else if (rowi < 576) v = w_kv[(rowi - 192) * CS + col];
        else if (rowi < 720) v = w_qp[(rowi - 576) * CS + col];
        else v = w_kvp[(rowi - 720) * CS + col];
        wqkv[idx] = v;
    }
    if (idx < QKV_DIM) {
        float v;
        if (idx < 192) v = b_q[idx];
        else if (idx < 576) v = b_kv[idx - 192];
        else if (idx < 720) v = b_qp[idx - 576];
        else v = b_kvp[idx - 720];
        bqkv[idx] = v;
    }
}

// ---------------- init quats (normalize) and trans (/SCALE) ------------------------
__global__ void init_kernel(const float* __restrict__ rq, const float* __restrict__ rt,
                            float* __restrict__ quats, float* __restrict__ trans)
{
    int i = blockIdx.x * 256 + threadIdx.x;
    if (i < N_RES) {
        float w = rq[i*4], x = rq[i*4+1], y = rq[i*4+2], z = rq[i*4+3];
        float n = 1.0f / sqrtf(w*w + x*x + y*y + z*z);
        quats[i*4] = w*n; quats[i*4+1] = x*n; quats[i*4+2] = y*n; quats[i*4+3] = z*n;
        trans[i*3] = rt[i*3] * 0.1f; trans[i*3+1] = rt[i*3+1] * 0.1f; trans[i*3+2] = rt[i*3+2] * 0.1f;
    }
}

// ---------------- quats -> rot matrix ---------------------------------------------
__global__ void rot_kernel(const float* __restrict__ quats, float* __restrict__ rot)
{
    int i = blockIdx.x * 256 + threadIdx.x;
    if (i < N_RES) {
        float w = quats[i*4], x = quats[i*4+1], y = quats[i*4+2], z = quats[i*4+3];
        float n = 1.0f / sqrtf(w*w + x*x + y*y + z*z);
        w *= n; x *= n; y *= n; z *= n;
        float* R = rot + i * 9;
        R[0] = 1 - 2*(y*y + z*z); R[1] = 2*(x*y - w*z);     R[2] = 2*(x*z + w*y);
        R[3] = 2*(x*y + w*z);     R[4] = 1 - 2*(x*x + z*z); R[5] = 2*(y*z - w*x);
        R[6] = 2*(x*z - w*y);     R[7] = 2*(y*z + w*x);     R[8] = 1 - 2*(x*x + y*y);
    }
}

// ---------------- point transforms + vcat assembly ---------------------------------
// qpts/kpts: [i][h][p][3] (per-head stride 12 floats); vcat: [j][h][40] = 16 v + 24 v_pts
__global__ __launch_bounds__(192) void transform_kernel(
    const float* __restrict__ qkv, const float* __restrict__ rot, const float* __restrict__ trans,
    float* __restrict__ qpts, float* __restrict__ kpts, float* __restrict__ vcat)
{
    int i = blockIdx.x, t = threadIdx.x;
    const float* R = rot + i * 9;
    float r0 = R[0], r1 = R[1], r2 = R[2], r3 = R[3], r4 = R[4], r5 = R[5], r6 = R[6], r7 = R[7], r8 = R[8];
    float tx = trans[i*3], ty = trans[i*3+1], tz = trans[i*3+2];
    const float* row = qkv + (size_t)i * QKV_DIM;
    if (t < 48) {               // q points: channel = 576 + x*48 + h*4 + pp ; t = h*4+pp
        float lx = row[576 + t], ly = row[576 + 48 + t], lz = row[576 + 96 + t];
        float gx = r0*lx + r1*ly + r2*lz + tx;
        float gy = r3*lx + r4*ly + r5*lz + ty;
        float gz = r6*lx + r7*ly + r8*lz + tz;
        float* o = qpts + (size_t)i * 144 + t * 3;    // h*12 + pp*3
        o[0] = gx; o[1] = gy; o[2] = gz;
    }
    if (t < 144) {              // kv points: channel = 720 + x*144 + h*12 + pp ; t = h*12+pp
        int h = t / 12, pp = t % 12;
        float lx = row[720 + t], ly = row[720 + 144 + t], lz = row[720 + 288 + t];
        float gx = r0*lx + r1*ly + r2*lz + tx;
        float gy = r3*lx + r4*ly + r5*lz + ty;
        float gz = r6*lx + r7*ly + r8*lz + tz;
        if (pp < 4) {
            float* o = kpts + (size_t)i * 144 + h * 12 + pp * 3;
            o[0] = gx; o[1] = gy; o[2] = gz;
        } else {
            float* o = vcat + (size_t)i * 480 + h * 40 + 16 + (pp - 4) * 3;
            o[0] = gx; o[1] = gy; o[2] = gz;
        }
    }
    {                           // v channels: kv section, second half of each 32
        int h = t >> 4, c = t & 15;
        vcat[(size_t)i * 480 + h * 40 + c] = row[192 + h * 32 + 16 + c];
    }
}

// ---------------- attention logits + softmax: a[h][i][j] ---------------------------
__global__ __launch_bounds__(256) void attn_kernel(
    const float* __restrict__ qkv, const float* __restrict__ qpts, const float* __restrict__ kpts,
    const float* __restrict__ bpair, const float* __restrict__ head_weights, float* __restrict__ a)
{
    int i = blockIdx.x, h = blockIdx.y;
    __shared__ float qs[CH], qps[12], shw[1];
    __shared__ float redm[4], reds[4];
    int t = threadIdx.x;
    if (t < CH) qs[t] = qkv[(size_t)i * QKV_DIM + h * CH + t];
    else if (t < CH + 12) qps[t - CH] = qpts[(size_t)i * 144 + h * 12 + (t - CH)];
    else if (t == 31) {
        float x = head_weights[h];
        float sp = (x > 20.f) ? x : log1pf(expf(x));
        shw[0] = sp * 0.13608276348f;   // softplus(hw) * sqrt(1/54)
    }
    __syncthreads();
    float hw = shw[0];
    float xv[2];
    #pragma unroll
    for (int r = 0; r < 2; ++r) {
        int j = t + r * 256;
        const float* kr = qkv + (size_t)j * QKV_DIM + 192 + h * 32;
        float dot = 0.f;
        #pragma unroll
        for (int c = 0; c < CH; ++c) dot += qs[c] * kr[c];
        const float* kp = kpts + (size_t)j * 144 + h * 12;
        float pt = 0.f;
        #pragma unroll
        for (int pc = 0; pc < 12; ++pc) { float d = qps[pc] - kp[pc]; pt += d * d; }
        xv[r] = dot * 0.14433756730f + bpair[((size_t)h * N_RES + i) * N_RES + j] - 0.5f * hw * pt;
    }
    float lm = fmaxf(xv[0], xv[1]);
    #pragma unroll
    for (int off = 32; off; off >>= 1) lm = fmaxf(lm, __shfl_xor(lm, off));
    if ((t & 63) == 0) redm[t >> 6] = lm;
    __syncthreads();
    float bmx = fmaxf(fmaxf(redm[0], redm[1]), fmaxf(redm[2], redm[3]));
    float e0 = expf(xv[0] - bmx), e1 = expf(xv[1] - bmx);
    float ls = e0 + e1;
    #pragma unroll
    for (int off = 32; off; off >>= 1) ls += __shfl_xor(ls, off);
    if ((t & 63) == 0) reds[t >> 6] = ls;
    __syncthreads();
    float inv = 1.0f / (reds[0] + reds[1] + reds[2] + reds[3]);
    float* arow = a + ((size_t)h * N_RES + i) * N_RES;
    arow[t] = e0 * inv;
    arow[t + 256] = e1 * inv;
}

// ---------------- o_tmp[h][i][40] = sum_j a[h][i][j] * vcat[j][h][40] --------------
__global__ __launch_bounds__(256) void ogemm_kernel(
    const float* __restrict__ a, const float* __restrict__ vcat, float* __restrict__ o_tmp)
{
    int h = blockIdx.y;
    int bm = blockIdx.x * 64;
    __shared__ float As[64][33];
    __shared__ float Vs[32][40];
    int t = threadIdx.x;
    int il_c = t & 63, ng = t >> 6;
    float acc[10];
    #pragma unroll
    for (int r = 0; r < 10; ++r) acc[r] = 0.f;
    for (int j0 = 0; j0 < N_RES; j0 += 32) {
        {
            int l = t * 8;
            int il = l >> 5, jl = l & 31;
            const float4* src = (const float4*)(a + ((size_t)h * N_RES + bm + il) * N_RES + j0 + jl);
            float4 v0 = src[0], v1 = src[1];
            As[il][jl]   = v0.x; As[il][jl+1] = v0.y; As[il][jl+2] = v0.z; As[il][jl+3] = v0.w;
            As[il][jl+4] = v1.x; As[il][jl+5] = v1.y; As[il][jl+6] = v1.z; As[il][jl+7] = v1.w;
        }
        #pragma unroll
        for (int r = 0; r < 5; ++r) {
            int l = t + 256 * r;
            int jj = l / 40, n = l % 40;
            Vs[jj][n] = vcat[(size_t)(j0 + jj) * 480 + h * 40 + n];
        }
        __syncthreads();
        #pragma unroll 8
        for (int jj = 0; jj < 32; ++jj) {
            float av = As[il_c][jj];
            #pragma unroll
            for (int r = 0; r < 10; ++r) acc[r] += av * Vs[jj][ng * 10 + r];
        }
        __syncthreads();
    }
    float* o = o_tmp + ((size_t)h * N_RES + bm + il_c) * 40 + ng * 10;
    #pragma unroll
    for (int r = 0; r < 10; ++r) o[r] = acc[r];
}

// ---------------- o_pair: cat[i][576 + h*128 + c] = sum_j a[h][i][j]*zln[i][j][c] --
__global__ __launch_bounds__(128) void opair_kernel(
    const float* __restrict__ z, const float* __restrict__ zstats, const float* __restrict__ a,
    const float* __restrict__ lng, const float* __restrict__ lnb, float* __restrict__ cat)
{
    int i = blockIdx.x;
    int c = threadIdx.x;   // 128
    __shared__ float als[HD][N_RES];
    __shared__ float zst[N_RES * 2];
    for (int idx = c; idx < HD * N_RES; idx += 128) {
        int h = idx >> 9, j = idx & 511;
        als[h][j] = a[((size_t)h * N_RES + i) * N_RES + j];
    }
    for (int idx = c; idx < N_RES * 2; idx += 128) zst[idx] = zstats[(size_t)i * N_RES * 2 + idx];
    __syncthreads();
    float g = lng[c], b = lnb[c];
    float acc[HD];
    #pragma unroll
    for (int h = 0; h < HD; ++h) acc[h] = 0.f;
    const float* zr = z + (size_t)i * N_RES * CZ + c;
    for (int j = 0; j < N_RES; ++j) {
        float m = zst[j * 2], r = zst[j * 2 + 1];
        float zn = (zr[(size_t)j * CZ] - m) * r * g + b;
        #pragma unroll
        for (int h = 0; h < HD; ++h) acc[h] += als[h][j] * zn;
    }
    float* o = cat + (size_t)i * CAT_DIM + 576;
    #pragma unroll
    for (int h = 0; h < HD; ++h) o[h * CZ + c] = acc[h];
}

// ---------------- cat[0:576): o copy + local frame points + norms ------------------
__global__ __launch_bounds__(192) void cat_kernel(
    const float* __restrict__ o_tmp, const float* __restrict__ rot, const float* __restrict__ trans,
    float* __restrict__ cat)
{
    int i = blockIdx.x, t = threadIdx.x;
    const float* R = rot + i * 9;
    float tx = trans[i*3], ty = trans[i*3+1], tz = trans[i*3+2];
    float* crow = cat + (size_t)i * CAT_DIM;
    {   // o channels: t = h*16 + c
        int h = t >> 4, c = t & 15;
        crow[t] = o_tmp[((size_t)h * N_RES + i) * 40 + c];
    }
    if (t < 96) {   // t = h*8 + p
        int h = t >> 3, p = t & 7;
        const float* og = o_tmp + ((size_t)h * N_RES + i) * 40 + 16 + p * 3;
        float dx = og[0] - tx, dy = og[1] - ty, dz = og[2] - tz;
        float lx = R[0]*dx + R[3]*dy + R[6]*dz;   // rot^T
        float ly = R[1]*dx + R[4]*dy + R[7]*dz;
        float lz = R[2]*dx + R[5]*dy + R[8]*dz;
        crow[192 + t] = lx;
        crow[288 + t] = ly;
        crow[384 + t] = lz;
        crow[480 + t] = sqrtf(lx*lx + ly*ly + lz*lz + 1e-8f);
    }
}

// ---------------- backbone update: upd, quat mul+norm, trans, frame out ------------
__global__ __launch_bounds__(256) void frame_kernel(
    const float* __restrict__ s, const float* __restrict__ w_bb, const float* __restrict__ b_bb,
    const float* __restrict__ rot, float* quats, float* trans, float* __restrict__ frames_out)
{
    int lane = threadIdx.x & 63;
    int i = (blockIdx.x * 256 + threadIdx.x) >> 6;
    const float* srow = s + (size_t)i * CS;
    float p[6];
    #pragma unroll
    for (int r = 0; r < 6; ++r) p[r] = 0.f;
    #pragma unroll
    for (int k = 0; k < 6; ++k) {
        int c = lane + k * 64;
        float sv = srow[c];
        #pragma unroll
        for (int r = 0; r < 6; ++r) p[r] += sv * w_bb[r * CS + c];
    }
    #pragma unroll
    for (int r = 0; r < 6; ++r)
        #pragma unroll
        for (int off = 32; off; off >>= 1) p[r] += __shfl_xor(p[r], off);
    if (lane == 0) {
        float u0 = p[0] + b_bb[0], u1 = p[1] + b_bb[1], u2 = p[2] + b_bb[2];
        float u3 = p[3] + b_bb[3], u4 = p[4] + b_bb[4], u5 = p[5] + b_bb[5];
        float qw = quats[i*4], qx = quats[i*4+1], qy = quats[i*4+2], qz = quats[i*4+3];
        float nw = qw - qx*u0 - qy*u1 - qz*u2;
        float nx = qw*u0 + qx + qy*u2 - qz*u1;
        float ny = qw*u1 - qx*u2 + qy + qz*u0;
        float nz = qw*u2 + qx*u1 - qy*u0 + qz;
        float n = 1.0f / sqrtf(nw*nw + nx*nx + ny*ny + nz*nz);
        nw *= n; nx *= n; ny *= n; nz *= n;
        const float* R = rot + i * 9;
        float t0 = trans[i*3+0] + R[0]*u3 + R[1]*u4 + R[2]*u5;
        float t1 = trans[i*3+1] + R[3]*u3 + R[4]*u4 + R[5]*u5;
        float t2 = trans[i*3+2] + R[6]*u3 + R[7]*u4 + R[8]*u5;
        quats[i*4] = nw; quats[i*4+1] = nx; quats[i*4+2] = ny; quats[i*4+3] = nz;
        trans[i*3] = t0; trans[i*3+1] = t1; trans[i*3+2] = t2;
        float* f = frames_out + (size_t)i * 7;
        f[0] = nw; f[1] = nx; f[2] = ny; f[3] = nz;
        f[4] = t0 * 10.f; f[5] = t1 * 10.f; f[6] = t2 * 10.f;
    }
}

extern "C" void kernel_launch(void* const* d_in, const int* in_sizes, int n_in,
                              void* d_out, int out_size, void* d_ws, size_t ws_size,
                              hipStream_t stream)
{
    const float* s_in  = (const float*)d_in[0];
    const float* z     = (const float*)d_in[1];
    const float* rq    = (const float*)d_in[2];
    const float* rt    = (const float*)d_in[3];
    const float* mask  = (const float*)d_in[4];
    const float* ln_s_g = (const float*)d_in[5];
    const float* ln_s_b = (const float*)d_in[6];
    const float* ln_z_g = (const float*)d_in[7];
    const float* ln_z_b = (const float*)d_in[8];
    const float* w_in  = (const float*)d_in[9];
    const float* b_in  = (const float*)d_in[10];
    const float* w_q   = (const float*)d_in[11];
    const float* b_q   = (const float*)d_in[12];
    const float* w_kv  = (const float*)d_in[13];
    const float* b_kv  = (const float*)d_in[14];
    const float* w_qp  = (const float*)d_in[15];
    const float* b_qp  = (const float*)d_in[16];
    const float* w_kvp = (const float*)d_in[17];
    const float* b_kvp = (const float*)d_in[18];
    const float* w_b   = (const float*)d_in[19];
    const float* b_b   = (const float*)d_in[20];
    const float* head_weights = (const float*)d_in[21];
    const float* w_o   = (const float*)d_in[22];
    const float* b_o   = (const float*)d_in[23];
    const float* ln_ipa_g = (const float*)d_in[24];
    const float* ln_ipa_b = (const float*)d_in[25];
    const float* ln_tr_g  = (const float*)d_in[26];
    const float* ln_tr_b  = (const float*)d_in[27];
    const float* w_t1  = (const float*)d_in[28];
    const float* b_t1  = (const float*)d_in[29];
    const float* w_t2  = (const float*)d_in[30];
    const float* b_t2  = (const float*)d_in[31];
    const float* w_t3  = (const float*)d_in[32];
    const float* b_t3  = (const float*)d_in[33];
    const float* w_bb  = (const float*)d_in[34];
    const float* b_bb  = (const float*)d_in[35];

    float* ws = (float*)d_ws;
    size_t off = 0;
    auto alloc = [&](size_t n) { float* p = ws + off; off += n; return p; };
    float* s_tmp   = alloc((size_t)N_RES * CS);
    float* t1      = alloc((size_t)N_RES * CS);
    float* t2      = alloc((size_t)N_RES * CS);
    float* zstats  = alloc((size_t)N_RES * N_RES * 2);
    float* bpair   = alloc((size_t)HD * N_RES * N_RES);
    float* abuf    = alloc((size_t)HD * N_RES * N_RES);
    float* qkv_all = alloc((size_t)N_RES * QKV_DIM);
    float* qpts    = alloc((size_t)N_RES * 144);
    float* kpts    = alloc((size_t)N_RES * 144);
    float* vcat    = alloc((size_t)N_RES * 480);
    float* o_tmp   = alloc((size_t)HD * N_RES * 40);
    float* cat     = alloc((size_t)N_RES * CAT_DIM);
    float* quats   = alloc((size_t)N_RES * 4);
    float* trans   = alloc((size_t)N_RES * 3 + 1);   // +1 keeps later bufs 16B-aligned
    float* rot     = alloc((size_t)N_RES * 9 + 3);
    float* wqkv    = alloc((size_t)QKV_DIM * CS);
    float* bqkv    = alloc((size_t)QKV_DIM);
    float* s_cur   = alloc((size_t)N_RES * CS);
    (void)ws_size; (void)in_sizes; (void)n_in; (void)out_size;

    // ---- preamble ----
    init_kernel<<<2, 256, 0, stream>>>(rq, rt, quats, trans);
    rowln_kernel<<<N_RES, 64, 0, stream>>>(s_in, s_tmp, ln_s_g, ln_s_b);
    gemm_mfma<<<dim3(CS / 64, N_RES / 64), 256, 0, stream>>>(s_tmp, w_in, b_in, nullptr, s_cur, N_RES, CS, CS, 0);
    zstats_kernel<<<(N_RES * N_RES) / 4, 256, 0, stream>>>(z, zstats);
    bpair_kernel<<<(N_RES * N_RES) / 256, 256, 0, stream>>>(z, zstats, ln_z_g, ln_z_b, w_b, b_b, mask, bpair);
    pack_kernel<<<(QKV_DIM * CS + 255) / 256, 256, 0, stream>>>(w_q, w_kv, w_qp, w_kvp, b_q, b_kv, b_qp, b_kvp, wqkv, bqkv);

    float* frames = (float*)d_out;
    for (int it = 0; it < 8; ++it) {
        rot_kernel<<<2, 256, 0, stream>>>(quats, rot);
        gemm_mfma<<<dim3(QKV_DIM / 64, N_RES / 64), 256, 0, stream>>>(s_cur, wqkv, bqkv, nullptr, qkv_all, N_RES, QKV_DIM, CS, 0);
        transform_kernel<<<N_RES, 192, 0, stream>>>(qkv_all, rot, trans, qpts, kpts, vcat);
        attn_kernel<<<dim3(N_RES, HD), 256, 0, stream>>>(qkv_all, qpts, kpts, bpair, head_weights, abuf);
        ogemm_kernel<<<dim3(N_RES / 64, HD), 256, 0, stream>>>(abuf, vcat, o_tmp);
        opair_kernel<<<N_RES, 128, 0, stream>>>(z, zstats, abuf, ln_z_g, ln_z_b, cat);
        cat_kernel<<<N_RES, 192, 0, stream>>>(o_tmp, rot, trans, cat);
        gemm_mfma<<<dim3(CS / 64, N_RES / 64), 256, 0, stream>>>(cat, w_o, b_o, s_cur, s_cur, N_RES, CS, CAT_DIM, 0);
        rowln_kernel<<<N_RES, 64, 0, stream>>>(s_cur, s_cur, ln_ipa_g, ln_ipa_b);
        gemm_mfma<<<dim3(CS / 64, N_RES / 64), 256, 0, stream>>>(s_cur, w_t1, b_t1, nullptr, t1, N_RES, CS, CS, 1);
        gemm_mfma<<<dim3(CS / 64, N_RES / 64), 256, 0, stream>>>(t1, w_t2, b_t2, nullptr, t2, N_RES, CS, CS, 1);
        gemm_mfma<<<dim3(CS / 64, N_RES / 64), 256, 0, stream>>>(t2, w_t3, b_t3, s_cur, s_cur, N_RES, CS, CS, 0);
        rowln_kernel<<<N_RES, 64, 0, stream>>>(s_cur, s_cur, ln_tr_g, ln_tr_b);
        frame_kernel<<<N_RES / 4, 256, 0, stream>>>(s_cur, w_bb, b_bb, rot, quats, trans, frames + (size_t)it * N_RES * 7);
    }
    hipMemcpyAsync(frames + 8 * N_RES * 7, s_cur, sizeof(float) * N_RES * CS,
                   hipMemcpyDeviceToDevice, stream);
}

// Round 8
// 2113.903 us; speedup vs baseline: 1.3984x; 1.1129x over previous
//
#include <hip/hip_runtime.h>
#include <math.h>

#define N_RES 512
#define CS 384
#define CZ 128
#define HD 12
#define CH 16
#define QKV_DIM 1152   // 192 q + 384 kv + 144 qp + 432 kvp
#define CAT_DIM 2112   // 192 o + 288 fl + 96 norm + 1536 opair
#define INF_F 100000.0f

typedef __attribute__((ext_vector_type(8))) __bf16 bf16x8;
typedef __attribute__((ext_vector_type(4))) float f32x4;

__device__ inline bf16x8 cvt8(float4 a, float4 b) {
    bf16x8 r;
    r[0] = (__bf16)a.x; r[1] = (__bf16)a.y; r[2] = (__bf16)a.z; r[3] = (__bf16)a.w;
    r[4] = (__bf16)b.x; r[5] = (__bf16)b.y; r[6] = (__bf16)b.z; r[7] = (__bf16)b.w;
    return r;
}

// quat (w,x,y,z) -> rot rows r[9]; quats assumed ~normalized, normalize anyway
__device__ inline void quat_rot(float w, float x, float y, float z, float* r) {
    float n = 1.0f / sqrtf(w*w + x*x + y*y + z*z);
    w *= n; x *= n; y *= n; z *= n;
    r[0] = 1 - 2*(y*y + z*z); r[1] = 2*(x*y - w*z);     r[2] = 2*(x*z + w*y);
    r[3] = 2*(x*y + w*z);     r[4] = 1 - 2*(x*x + z*z); r[5] = 2*(y*z - w*x);
    r[6] = 2*(x*z - w*y);     r[7] = 2*(y*z + w*x);     r[8] = 1 - 2*(x*x + y*y);
}

// ---------------- MFMA bf16 GEMM: out = act(A[M,K]@W[Nn,K]^T + bias (+res)) -------
// M%64==0, Nn%64==0, K%64==0. Block 256 thr = 4 waves (2x2), 64x64 tile, K-step 64.
__global__ __launch_bounds__(256) void gemm_mfma(
    const float* __restrict__ A, const float* __restrict__ W,
    const float* __restrict__ bias, const float* res, float* out,
    int M, int Nn, int K, int relu)
{
    __shared__ __bf16 Asl[64 * 64];
    __shared__ __bf16 Bsl[64 * 64];
    int bm = blockIdx.y * 64;
    int bn = blockIdx.x * 64;
    int tid = threadIdx.x;

    int tr = tid >> 2;
    int tu = (tid & 3) * 2;
    const float* ga0 = A + (size_t)(bm + tr) * K + tu * 8;
    const float* gb0 = W + (size_t)(bn + tr) * K + tu * 8;

    int lane = tid & 63;
    int w = tid >> 6;
    int wr = w >> 1, wc = w & 1;
    int lr = lane & 15, lg = lane >> 4;
    int arow0 = wr * 32 + lr, arow1 = arow0 + 16;
    int brow0 = wc * 32 + lr, brow1 = brow0 + 16;

    f32x4 acc00 = {0.f, 0.f, 0.f, 0.f}, acc01 = {0.f, 0.f, 0.f, 0.f};
    f32x4 acc10 = {0.f, 0.f, 0.f, 0.f}, acc11 = {0.f, 0.f, 0.f, 0.f};

    float4 ra0, ra1, ra2, ra3, rb0, rb1, rb2, rb3;
    ra0 = ((const float4*)ga0)[0]; ra1 = ((const float4*)ga0)[1];
    ra2 = ((const float4*)ga0)[2]; ra3 = ((const float4*)ga0)[3];
    rb0 = ((const float4*)gb0)[0]; rb1 = ((const float4*)gb0)[1];
    rb2 = ((const float4*)gb0)[2]; rb3 = ((const float4*)gb0)[3];

    int u0 = tu ^ (tr & 7);
    int u1 = (tu + 1) ^ (tr & 7);

    for (int k0 = 0; k0 < K; k0 += 64) {
        __syncthreads();
        *(bf16x8*)(Asl + tr * 64 + u0 * 8) = cvt8(ra0, ra1);
        *(bf16x8*)(Asl + tr * 64 + u1 * 8) = cvt8(ra2, ra3);
        *(bf16x8*)(Bsl + tr * 64 + u0 * 8) = cvt8(rb0, rb1);
        *(bf16x8*)(Bsl + tr * 64 + u1 * 8) = cvt8(rb2, rb3);
        __syncthreads();
        if (k0 + 64 < K) {
            const float* ga = ga0 + k0 + 64;
            const float* gb = gb0 + k0 + 64;
            ra0 = ((const float4*)ga)[0]; ra1 = ((const float4*)ga)[1];
            ra2 = ((const float4*)ga)[2]; ra3 = ((const float4*)ga)[3];
            rb0 = ((const float4*)gb)[0]; rb1 = ((const float4*)gb)[1];
            rb2 = ((const float4*)gb)[2]; rb3 = ((const float4*)gb)[3];
        }
        #pragma unroll
        for (int ks = 0; ks < 2; ++ks) {
            int ub = ks * 4 + lg;
            bf16x8 a0 = *(bf16x8*)(Asl + arow0 * 64 + (ub ^ (lr & 7)) * 8);
            bf16x8 a1 = *(bf16x8*)(Asl + arow1 * 64 + (ub ^ (lr & 7)) * 8);
            bf16x8 b0 = *(bf16x8*)(Bsl + brow0 * 64 + (ub ^ (lr & 7)) * 8);
            bf16x8 b1 = *(bf16x8*)(Bsl + brow1 * 64 + (ub ^ (lr & 7)) * 8);
            acc00 = __builtin_amdgcn_mfma_f32_16x16x32_bf16(a0, b0, acc00, 0, 0, 0);
            acc01 = __builtin_amdgcn_mfma_f32_16x16x32_bf16(a0, b1, acc01, 0, 0, 0);
            acc10 = __builtin_amdgcn_mfma_f32_16x16x32_bf16(a1, b0, acc10, 0, 0, 0);
            acc11 = __builtin_amdgcn_mfma_f32_16x16x32_bf16(a1, b1, acc11, 0, 0, 0);
        }
    }

    int mb = bm + wr * 32, nb = bn + wc * 32;
    #pragma unroll
    for (int fm = 0; fm < 2; ++fm) {
        #pragma unroll
        for (int fn = 0; fn < 2; ++fn) {
            f32x4 acc = fm == 0 ? (fn == 0 ? acc00 : acc01) : (fn == 0 ? acc10 : acc11);
            int n = nb + fn * 16 + lr;
            float bi = bias[n];
            int m0 = mb + fm * 16 + lg * 4;
            #pragma unroll
            for (int r = 0; r < 4; ++r) {
                float v = acc[r] + bi;
                if (res) v += res[(size_t)(m0 + r) * Nn + n];
                if (relu) v = fmaxf(v, 0.f);
                out[(size_t)(m0 + r) * Nn + n] = v;
            }
        }
    }
}

// ---------------- row LayerNorm over CS=384 ---------------------------------------
__global__ __launch_bounds__(64) void rowln_kernel(
    const float* in, float* out, const float* __restrict__ g, const float* __restrict__ b)
{
    int row = blockIdx.x;
    int lane = threadIdx.x;
    const float* x = in + (size_t)row * CS;
    float v[6];
    float s = 0.f, sq = 0.f;
    #pragma unroll
    for (int k = 0; k < 6; ++k) {
        v[k] = x[lane + k * 64];
        s += v[k]; sq += v[k] * v[k];
    }
    #pragma unroll
    for (int off = 32; off; off >>= 1) { s += __shfl_xor(s, off); sq += __shfl_xor(sq, off); }
    float mean = s * (1.0f / CS);
    float var = sq * (1.0f / CS) - mean * mean;
    float rstd = 1.0f / sqrtf(var + 1e-5f);
    float* o = out + (size_t)row * CS;
    #pragma unroll
    for (int k = 0; k < 6; ++k) {
        int c = lane + k * 64;
        o[c] = (v[k] - mean) * rstd * g[c] + b[c];
    }
}

// ---------------- z row stats (mean, rstd) over CZ=128 ----------------------------
__global__ __launch_bounds__(256) void zstats_kernel(const float* __restrict__ z, float* __restrict__ zstats)
{
    int wid = threadIdx.x >> 6;
    int lane = threadIdx.x & 63;
    size_t row = (size_t)blockIdx.x * 4 + wid;
    const float* x = z + row * CZ;
    float a = x[lane], b = x[lane + 64];
    float s = a + b, sq = a * a + b * b;
    #pragma unroll
    for (int off = 32; off; off >>= 1) { s += __shfl_xor(s, off); sq += __shfl_xor(sq, off); }
    if (lane == 0) {
        float mean = s * (1.0f / CZ);
        float var = sq * (1.0f / CZ) - mean * mean;
        zstats[row * 2] = mean;
        zstats[row * 2 + 1] = 1.0f / sqrtf(var + 1e-5f);
    }
}

// ---------------- pair bias (+mask) precompute: bpair[h][i][j] ---------------------
__global__ __launch_bounds__(256) void bpair_kernel(
    const float* __restrict__ z, const float* __restrict__ zstats,
    const float* __restrict__ lng, const float* __restrict__ lnb,
    const float* __restrict__ w_b, const float* __restrict__ b_b,
    const float* __restrict__ mask, float* __restrict__ bpair)
{
    __shared__ float wbs[HD][CZ];
    __shared__ float gs[CZ], bs[CZ];
    for (int idx = threadIdx.x; idx < HD * CZ; idx += 256) wbs[idx / CZ][idx % CZ] = w_b[idx];
    if (threadIdx.x < CZ) { gs[threadIdx.x] = lng[threadIdx.x]; bs[threadIdx.x] = lnb[threadIdx.x]; }
    __syncthreads();
    size_t row = (size_t)blockIdx.x * 256 + threadIdx.x;   // i*512 + j
    int i = (int)(row >> 9), j = (int)(row & 511);
    const float* zr = z + row * CZ;
    float m = zstats[row * 2], r = zstats[row * 2 + 1];
    float acc[HD];
    #pragma unroll
    for (int h = 0; h < HD; ++h) acc[h] = 0.f;
    for (int c = 0; c < CZ; c += 4) {
        float4 zv = *(const float4*)(zr + c);
        float zn0 = (zv.x - m) * r * gs[c] + bs[c];
        float zn1 = (zv.y - m) * r * gs[c+1] + bs[c+1];
        float zn2 = (zv.z - m) * r * gs[c+2] + bs[c+2];
        float zn3 = (zv.w - m) * r * gs[c+3] + bs[c+3];
        #pragma unroll
        for (int h = 0; h < HD; ++h)
            acc[h] += zn0 * wbs[h][c] + zn1 * wbs[h][c+1] + zn2 * wbs[h][c+2] + zn3 * wbs[h][c+3];
    }
    float mterm = INF_F * (mask[i] * mask[j] - 1.0f);
    #pragma unroll
    for (int h = 0; h < HD; ++h)
        bpair[((size_t)h * N_RES + i) * N_RES + j] = 0.57735026919f * (acc[h] + b_b[h]) + mterm;
}

// ---------------- pack qkv weights -------------------------------------------------
__global__ __launch_bounds__(256) void pack_kernel(
    const float* __restrict__ w_q, const float* __restrict__ w_kv,
    const float* __restrict__ w_qp, const float* __restrict__ w_kvp,
    const float* __restrict__ b_q, const float* __restrict__ b_kv,
    const float* __restrict__ b_qp, const float* __restrict__ b_kvp,
    float* __restrict__ wqkv, float* __restrict__ bqkv)
{
    int idx = blockIdx.x * 256 + threadIdx.x;
    if (idx < QKV_DIM * CS) {
        int rowi = idx / CS, col = idx % CS;
        float v;
        if (rowi < 192) v = w_q[rowi * CS + col];
        else if (rowi < 576) v = w_kv[(rowi - 192) * CS + col];
        else if (rowi < 720) v = w_qp[(rowi - 576) * CS + col];
        else v = w_kvp[(rowi - 720) * CS + col];
        wqkv[idx] = v;
    }
    if (idx < QKV_DIM) {
        float v;
        if (idx < 192) v = b_q[idx];
        else if (idx < 576) v = b_kv[idx - 192];
        else if (idx < 720) v = b_qp[idx - 576];
        else v = b_kvp[idx - 720];
        bqkv[idx] = v;
    }
}

// ---------------- init quats (normalize) and trans (/SCALE) ------------------------
__global__ void init_kernel(const float* __restrict__ rq, const float* __restrict__ rt,
                            float* __restrict__ quats, float* __restrict__ trans)
{
    int i = blockIdx.x * 256 + threadIdx.x;
    if (i < N_RES) {
        float w = rq[i*4], x = rq[i*4+1], y = rq[i*4+2], z = rq[i*4+3];
        float n = 1.0f / sqrtf(w*w + x*x + y*y + z*z);
        quats[i*4] = w*n; quats[i*4+1] = x*n; quats[i*4+2] = y*n; quats[i*4+3] = z*n;
        trans[i*3] = rt[i*3] * 0.1f; trans[i*3+1] = rt[i*3+1] * 0.1f; trans[i*3+2] = rt[i*3+2] * 0.1f;
    }
}

// ---------------- point transforms + vcat assembly (R from quats inline) ----------
__global__ __launch_bounds__(192) void transform_kernel(
    const float* __restrict__ qkv, const float* __restrict__ quats, const float* __restrict__ trans,
    float* __restrict__ qpts, float* __restrict__ kpts, float* __restrict__ vcat)
{
    int i = blockIdx.x, t = threadIdx.x;
    float R[9];
    quat_rot(quats[i*4], quats[i*4+1], quats[i*4+2], quats[i*4+3], R);
    float tx = trans[i*3], ty = trans[i*3+1], tz = trans[i*3+2];
    const float* row = qkv + (size_t)i * QKV_DIM;
    if (t < 48) {               // q points: t = h*4+pp
        float lx = row[576 + t], ly = row[576 + 48 + t], lz = row[576 + 96 + t];
        float gx = R[0]*lx + R[1]*ly + R[2]*lz + tx;
        float gy = R[3]*lx + R[4]*ly + R[5]*lz + ty;
        float gz = R[6]*lx + R[7]*ly + R[8]*lz + tz;
        float* o = qpts + (size_t)i * 144 + t * 3;
        o[0] = gx; o[1] = gy; o[2] = gz;
    }
    if (t < 144) {              // kv points: t = h*12+pp
        int h = t / 12, pp = t % 12;
        float lx = row[720 + t], ly = row[720 + 144 + t], lz = row[720 + 288 + t];
        float gx = R[0]*lx + R[1]*ly + R[2]*lz + tx;
        float gy = R[3]*lx + R[4]*ly + R[5]*lz + ty;
        float gz = R[6]*lx + R[7]*ly + R[8]*lz + tz;
        if (pp < 4) {
            float* o = kpts + (size_t)i * 144 + h * 12 + pp * 3;
            o[0] = gx; o[1] = gy; o[2] = gz;
        } else {
            float* o = vcat + (size_t)i * 480 + h * 40 + 16 + (pp - 4) * 3;
            o[0] = gx; o[1] = gy; o[2] = gz;
        }
    }
    {                           // v channels
        int h = t >> 4, c = t & 15;
        vcat[(size_t)i * 480 + h * 40 + c] = row[192 + h * 32 + 16 + c];
    }
}

// ---------------- attention logits + softmax: a[h][i][j] ---------------------------
__global__ __launch_bounds__(256) void attn_kernel(
    const float* __restrict__ qkv, const float* __restrict__ qpts, const float* __restrict__ kpts,
    const float* __restrict__ bpair, const float* __restrict__ head_weights, float* __restrict__ a)
{
    int i = blockIdx.x, h = blockIdx.y;
    __shared__ float qs[CH], qps[12], shw[1];
    __shared__ float redm[4], reds[4];
    int t = threadIdx.x;
    if (t < CH) qs[t] = qkv[(size_t)i * QKV_DIM + h * CH + t];
    else if (t < CH + 12) qps[t - CH] = qpts[(size_t)i * 144 + h * 12 + (t - CH)];
    else if (t == 31) {
        float x = head_weights[h];
        float sp = (x > 20.f) ? x : log1pf(expf(x));
        shw[0] = sp * 0.13608276348f;
    }
    __syncthreads();
    float hw = shw[0];
    float xv[2];
    #pragma unroll
    for (int r = 0; r < 2; ++r) {
        int j = t + r * 256;
        const float* kr = qkv + (size_t)j * QKV_DIM + 192 + h * 32;
        float dot = 0.f;
        #pragma unroll
        for (int c = 0; c < CH; ++c) dot += qs[c] * kr[c];
        const float* kp = kpts + (size_t)j * 144 + h * 12;
        float pt = 0.f;
        #pragma unroll
        for (int pc = 0; pc < 12; ++pc) { float d = qps[pc] - kp[pc]; pt += d * d; }
        xv[r] = dot * 0.14433756730f + bpair[((size_t)h * N_RES + i) * N_RES + j] - 0.5f * hw * pt;
    }
    float lm = fmaxf(xv[0], xv[1]);
    #pragma unroll
    for (int off = 32; off; off >>= 1) lm = fmaxf(lm, __shfl_xor(lm, off));
    if ((t & 63) == 0) redm[t >> 6] = lm;
    __syncthreads();
    float bmx = fmaxf(fmaxf(redm[0], redm[1]), fmaxf(redm[2], redm[3]));
    float e0 = expf(xv[0] - bmx), e1 = expf(xv[1] - bmx);
    float ls = e0 + e1;
    #pragma unroll
    for (int off = 32; off; off >>= 1) ls += __shfl_xor(ls, off);
    if ((t & 63) == 0) reds[t >> 6] = ls;
    __syncthreads();
    float inv = 1.0f / (reds[0] + reds[1] + reds[2] + reds[3]);
    float* arow = a + ((size_t)h * N_RES + i) * N_RES;
    arow[t] = e0 * inv;
    arow[t + 256] = e1 * inv;
}

// ---------------- o_tmp[h][i][40] = sum_j a[h][i][j] * vcat[j][h][40] --------------
__global__ __launch_bounds__(256) void ogemm_kernel(
    const float* __restrict__ a, const float* __restrict__ vcat, float* __restrict__ o_tmp)
{
    int h = blockIdx.y;
    int bm = blockIdx.x * 64;
    __shared__ float As[64][33];
    __shared__ float Vs[32][40];
    int t = threadIdx.x;
    int il_c = t & 63, ng = t >> 6;
    float acc[10];
    #pragma unroll
    for (int r = 0; r < 10; ++r) acc[r] = 0.f;
    for (int j0 = 0; j0 < N_RES; j0 += 32) {
        {
            int l = t * 8;
            int il = l >> 5, jl = l & 31;
            const float4* src = (const float4*)(a + ((size_t)h * N_RES + bm + il) * N_RES + j0 + jl);
            float4 v0 = src[0], v1 = src[1];
            As[il][jl]   = v0.x; As[il][jl+1] = v0.y; As[il][jl+2] = v0.z; As[il][jl+3] = v0.w;
            As[il][jl+4] = v1.x; As[il][jl+5] = v1.y; As[il][jl+6] = v1.z; As[il][jl+7] = v1.w;
        }
        #pragma unroll
        for (int r = 0; r < 5; ++r) {
            int l = t + 256 * r;
            int jj = l / 40, n = l % 40;
            Vs[jj][n] = vcat[(size_t)(j0 + jj) * 480 + h * 40 + n];
        }
        __syncthreads();
        #pragma unroll 8
        for (int jj = 0; jj < 32; ++jj) {
            float av = As[il_c][jj];
            #pragma unroll
            for (int r = 0; r < 10; ++r) acc[r] += av * Vs[jj][ng * 10 + r];
        }
        __syncthreads();
    }
    float* o = o_tmp + ((size_t)h * N_RES + bm + il_c) * 40 + ng * 10;
    #pragma unroll
    for (int r = 0; r < 10; ++r) o[r] = acc[r];
}

// ---------------- o_pair: j-split x4, 512 threads ----------------------------------
// cat[i][576 + h*128 + c] = sum_j a[h][i][j] * zln[i][j][c]
__global__ __launch_bounds__(512) void opair_kernel(
    const float* __restrict__ z, const float* __restrict__ zstats, const float* __restrict__ a,
    const float* __restrict__ lng, const float* __restrict__ lnb, float* __restrict__ cat)
{
    int i = blockIdx.x;
    int t = threadIdx.x;          // 512
    int c = t & 127, jg = t >> 7; // 4 j-groups of 128
    __shared__ float als[HD][N_RES];     // 24 KB
    __shared__ float zst[N_RES * 2];     // 4 KB
    __shared__ float pacc[4][HD][CZ];    // 24 KB
    for (int idx = t; idx < HD * N_RES; idx += 512) {
        int h = idx >> 9, j = idx & 511;
        als[h][j] = a[((size_t)h * N_RES + i) * N_RES + j];
    }
    for (int idx = t; idx < N_RES * 2; idx += 512) zst[idx] = zstats[(size_t)i * N_RES * 2 + idx];
    __syncthreads();
    float g = lng[c], b = lnb[c];
    float acc[HD];
    #pragma unroll
    for (int h = 0; h < HD; ++h) acc[h] = 0.f;
    const float* zr = z + ((size_t)i * N_RES + jg * 128) * CZ + c;
    for (int jj = 0; jj < 128; ++jj) {
        int j = jg * 128 + jj;
        float m = zst[j * 2], r = zst[j * 2 + 1];
        float zn = (zr[(size_t)jj * CZ] - m) * r * g + b;
        #pragma unroll
        for (int h = 0; h < HD; ++h) acc[h] += als[h][j] * zn;
    }
    #pragma unroll
    for (int h = 0; h < HD; ++h) pacc[jg][h][c] = acc[h];
    __syncthreads();
    #pragma unroll
    for (int k = 0; k < 3; ++k) {       // 1536 outputs / 512 threads
        int idx = t + k * 512;
        int h = idx >> 7, cc = idx & 127;
        float v = pacc[0][h][cc] + pacc[1][h][cc] + pacc[2][h][cc] + pacc[3][h][cc];
        cat[(size_t)i * CAT_DIM + 576 + h * CZ + cc] = v;
    }
}

// ---------------- cat[0:576): o copy + local frame points + norms ------------------
__global__ __launch_bounds__(192) void cat_kernel(
    const float* __restrict__ o_tmp, const float* __restrict__ quats, const float* __restrict__ trans,
    float* __restrict__ cat)
{
    int i = blockIdx.x, t = threadIdx.x;
    float R[9];
    quat_rot(quats[i*4], quats[i*4+1], quats[i*4+2], quats[i*4+3], R);
    float tx = trans[i*3], ty = trans[i*3+1], tz = trans[i*3+2];
    float* crow = cat + (size_t)i * CAT_DIM;
    {   // o channels: t = h*16 + c
        int h = t >> 4, c = t & 15;
        crow[t] = o_tmp[((size_t)h * N_RES + i) * 40 + c];
    }
    if (t < 96) {   // t = h*8 + p
        int h = t >> 3, p = t & 7;
        const float* og = o_tmp + ((size_t)h * N_RES + i) * 40 + 16 + p * 3;
        float dx = og[0] - tx, dy = og[1] - ty, dz = og[2] - tz;
        float lx = R[0]*dx + R[3]*dy + R[6]*dz;   // rot^T
        float ly = R[1]*dx + R[4]*dy + R[7]*dz;
        float lz = R[2]*dx + R[5]*dy + R[8]*dz;
        crow[192 + t] = lx;
        crow[288 + t] = ly;
        crow[384 + t] = lz;
        crow[480 + t] = sqrtf(lx*lx + ly*ly + lz*lz + 1e-8f);
    }
}

// ---------------- backbone update (R from quats inline) ----------------------------
__global__ __launch_bounds__(256) void frame_kernel(
    const float* __restrict__ s, const float* __restrict__ w_bb, const float* __restrict__ b_bb,
    float* quats, float* trans, float* __restrict__ frames_out)
{
    int lane = threadIdx.x & 63;
    int i = (blockIdx.x * 256 + threadIdx.x) >> 6;
    const float* srow = s + (size_t)i * CS;
    float p[6];
    #pragma unroll
    for (int r = 0; r < 6; ++r) p[r] = 0.f;
    #pragma unroll
    for (int k = 0; k < 6; ++k) {
        int c = lane + k * 64;
        float sv = srow[c];
        #pragma unroll
        for (int r = 0; r < 6; ++r) p[r] += sv * w_bb[r * CS + c];
    }
    #pragma unroll
    for (int r = 0; r < 6; ++r)
        #pragma unroll
        for (int off = 32; off; off >>= 1) p[r] += __shfl_xor(p[r], off);
    if (lane == 0) {
        float u0 = p[0] + b_bb[0], u1 = p[1] + b_bb[1], u2 = p[2] + b_bb[2];
        float u3 = p[3] + b_bb[3], u4 = p[4] + b_bb[4], u5 = p[5] + b_bb[5];
        float qw = quats[i*4], qx = quats[i*4+1], qy = quats[i*4+2], qz = quats[i*4+3];
        float R[9];
        quat_rot(qw, qx, qy, qz, R);            // pre-update rotation
        float nw = qw - qx*u0 - qy*u1 - qz*u2;  // quat mul with (1,u0,u1,u2)
        float nx = qw*u0 + qx + qy*u2 - qz*u1;
        float ny = qw*u1 - qx*u2 + qy + qz*u0;
        float nz = qw*u2 + qx*u1 - qy*u0 + qz;
        float n = 1.0f / sqrtf(nw*nw + nx*nx + ny*ny + nz*nz);
        nw *= n; nx *= n; ny *= n; nz *= n;
        float t0 = trans[i*3+0] + R[0]*u3 + R[1]*u4 + R[2]*u5;
        float t1 = trans[i*3+1] + R[3]*u3 + R[4]*u4 + R[5]*u5;
        float t2 = trans[i*3+2] + R[6]*u3 + R[7]*u4 + R[8]*u5;
        quats[i*4] = nw; quats[i*4+1] = nx; quats[i*4+2] = ny; quats[i*4+3] = nz;
        trans[i*3] = t0; trans[i*3+1] = t1; trans[i*3+2] = t2;
        float* f = frames_out + (size_t)i * 7;
        f[0] = nw; f[1] = nx; f[2] = ny; f[3] = nz;
        f[4] = t0 * 10.f; f[5] = t1 * 10.f; f[6] = t2 * 10.f;
    }
}

extern "C" void kernel_launch(void* const* d_in, const int* in_sizes, int n_in,
                              void* d_out, int out_size, void* d_ws, size_t ws_size,
                              hipStream_t stream)
{
    const float* s_in  = (const float*)d_in[0];
    const float* z     = (const float*)d_in[1];
    const float* rq    = (const float*)d_in[2];
    const float* rt    = (const float*)d_in[3];
    const float* mask  = (const float*)d_in[4];
    const float* ln_s_g = (const float*)d_in[5];
    const float* ln_s_b = (const float*)d_in[6];
    const float* ln_z_g = (const float*)d_in[7];
    const float* ln_z_b = (const float*)d_in[8];
    const float* w_in  = (const float*)d_in[9];
    const float* b_in  = (const float*)d_in[10];
    const float* w_q   = (const float*)d_in[11];
    const float* b_q   = (const float*)d_in[12];
    const float* w_kv  = (const float*)d_in[13];
    const float* b_kv  = (const float*)d_in[14];
    const float* w_qp  = (const float*)d_in[15];
    const float* b_qp  = (const float*)d_in[16];
    const float* w_kvp = (const float*)d_in[17];
    const float* b_kvp = (const float*)d_in[18];
    const float* w_b   = (const float*)d_in[19];
    const float* b_b   = (const float*)d_in[20];
    const float* head_weights = (const float*)d_in[21];
    const float* w_o   = (const float*)d_in[22];
    const float* b_o   = (const float*)d_in[23];
    const float* ln_ipa_g = (const float*)d_in[24];
    const float* ln_ipa_b = (const float*)d_in[25];
    const float* ln_tr_g  = (const float*)d_in[26];
    const float* ln_tr_b  = (const float*)d_in[27];
    const float* w_t1  = (const float*)d_in[28];
    const float* b_t1  = (const float*)d_in[29];
    const float* w_t2  = (const float*)d_in[30];
    const float* b_t2  = (const float*)d_in[31];
    const float* w_t3  = (const float*)d_in[32];
    const float* b_t3  = (const float*)d_in[33];
    const float* w_bb  = (const float*)d_in[34];
    const float* b_bb  = (const float*)d_in[35];

    float* ws = (float*)d_ws;
    size_t off = 0;
    auto alloc = [&](size_t n) { float* p = ws + off; off += n; return p; };
    float* s_tmp   = alloc((size_t)N_RES * CS);
    float* t1      = alloc((size_t)N_RES * CS);
    float* t2      = alloc((size_t)N_RES * CS);
    float* zstats  = alloc((size_t)N_RES * N_RES * 2);
    float* bpair   = alloc((size_t)HD * N_RES * N_RES);
    float* abuf    = alloc((size_t)HD * N_RES * N_RES);
    float* qkv_all = alloc((size_t)N_RES * QKV_DIM);
    float* qpts    = alloc((size_t)N_RES * 144);
    float* kpts    = alloc((size_t)N_RES * 144);
    float* vcat    = alloc((size_t)N_RES * 480);
    float* o_tmp   = alloc((size_t)HD * N_RES * 40);
    float* cat     = alloc((size_t)N_RES * CAT_DIM);
    float* quats   = alloc((size_t)N_RES * 4);
    float* trans   = alloc((size_t)N_RES * 3 + 1);   // +1 keeps later bufs 16B-aligned
    float* wqkv    = alloc((size_t)QKV_DIM * CS);
    float* bqkv    = alloc((size_t)QKV_DIM);
    float* s_cur   = alloc((size_t)N_RES * CS);
    (void)ws_size; (void)in_sizes; (void)n_in; (void)out_size;

    // ---- preamble ----
    init_kernel<<<2, 256, 0, stream>>>(rq, rt, quats, trans);
    rowln_kernel<<<N_RES, 64, 0, stream>>>(s_in, s_tmp, ln_s_g, ln_s_b);
    gemm_mfma<<<dim3(CS / 64, N_RES / 64), 256, 0, stream>>>(s_tmp, w_in, b_in, nullptr, s_cur, N_RES, CS, CS, 0);
    zstats_kernel<<<(N_RES * N_RES) / 4, 256, 0, stream>>>(z, zstats);
    bpair_kernel<<<(N_RES * N_RES) / 256, 256, 0, stream>>>(z, zstats, ln_z_g, ln_z_b, w_b, b_b, mask, bpair);
    pack_kernel<<<(QKV_DIM * CS + 255) / 256, 256, 0, stream>>>(w_q, w_kv, w_qp, w_kvp, b_q, b_kv, b_qp, b_kvp, wqkv, bqkv);

    float* frames = (float*)d_out;
    for (int it = 0; it < 8; ++it) {
        gemm_mfma<<<dim3(QKV_DIM / 64, N_RES / 64), 256, 0, stream>>>(s_cur, wqkv, bqkv, nullptr, qkv_all, N_RES, QKV_DIM, CS, 0);
        transform_kernel<<<N_RES, 192, 0, stream>>>(qkv_all, quats, trans, qpts, kpts, vcat);
        attn_kernel<<<dim3(N_RES, HD), 256, 0, stream>>>(qkv_all, qpts, kpts, bpair, head_weights, abuf);
        ogemm_kernel<<<dim3(N_RES / 64, HD), 256, 0, stream>>>(abuf, vcat, o_tmp);
        opair_kernel<<<N_RES, 512, 0, stream>>>(z, zstats, abuf, ln_z_g, ln_z_b, cat);
        cat_kernel<<<N_RES, 192, 0, stream>>>(o_tmp, quats, trans, cat);
        gemm_mfma<<<dim3(CS / 64, N_RES / 64), 256, 0, stream>>>(cat, w_o, b_o, s_cur, s_cur, N_RES, CS, CAT_DIM, 0);
        rowln_kernel<<<N_RES, 64, 0, stream>>>(s_cur, s_cur, ln_ipa_g, ln_ipa_b);
        gemm_mfma<<<dim3(CS / 64, N_RES / 64), 256, 0, stream>>>(s_cur, w_t1, b_t1, nullptr, t1, N_RES, CS, CS, 1);
        gemm_mfma<<<dim3(CS / 64, N_RES / 64), 256, 0, stream>>>(t1, w_t2, b_t2, nullptr, t2, N_RES, CS, CS, 1);
        gemm_mfma<<<dim3(CS / 64, N_RES / 64), 256, 0, stream>>>(t2, w_t3, b_t3, s_cur, s_cur, N_RES, CS, CS, 0);
        rowln_kernel<<<N_RES, 64, 0, stream>>>(s_cur, s_cur, ln_tr_g, ln_tr_b);
        frame_kernel<<<N_RES / 4, 256, 0, stream>>>(s_cur, w_bb, b_bb, quats, trans, frames + (size_t)it * N_RES * 7);
    }
    hipMemcpyAsync(frames + 8 * N_RES * 7, s_cur, sizeof(float) * N_RES * CS,
                   hipMemcpyDeviceToDevice, stream);
}